// Round 18
// baseline (8025.265 us; speedup 1.0000x reference)
//
#include <hip/hip_runtime.h>
#include <stdint.h>

typedef short short8 __attribute__((ext_vector_type(8)));
typedef float f32x4 __attribute__((ext_vector_type(4)));
typedef int int4v __attribute__((ext_vector_type(4)));
typedef unsigned short u16;

#define MFMA16(a, b, c) __builtin_amdgcn_mfma_f32_16x16x32_bf16((a), (b), (c), 0, 0, 0)

#define T_LEN 512
#define BATCH 64
#define EMB_D 512
#define HID 1024
#define VOC 256
#define NWG 128
#define RNN_THREADS 512
#define R0 256                                // h0 ring slots
#define R1 8                                  // h1 ring slots
#define SLOT (BATCH * HID)                    // u16 elems per ring slot (65536)

// -------- workspace layout (bytes) --------
#define OFF_XT    0u                          // int xT[512][64]
#define OFF_EMBT  131072u                     // bf16 embtab[256][512]
#define OFF_WIH0  524288u                     // bf16 [3072][512]
#define OFF_WHH0  3670016u                    // bf16 [3072][1024]
#define OFF_WIH1  9961472u
#define OFF_WHH1  16252928u
#define OFF_WOUT  22544384u                   // bf16 [256][1024]
#define OFF_H0R   23068672u                   // bf16 ring[256][64][1024]  (32 MB)
#define OFF_H1R   56623104u                   // bf16 ring[8][64][1024]    (1 MB)
#define OFF_H1ALL 57671680u                   // bf16 h1_all[512*64][1024] (64 MB)
#define OFF_SYNC  124780544u                  // p0[64]+p1[64] flag lines, 128B apart
#define SYNC_BYTES 16640u
#define WS_TOTAL  (OFF_SYNC + SYNC_BYTES)

static __device__ __forceinline__ u16 f2b(float f) {
  uint32_t u = __float_as_uint(f);
  u += 0x7FFFu + ((u >> 16) & 1u);   // round-to-nearest-even
  return (u16)(u >> 16);
}
static __device__ __forceinline__ float sigm(float x) { return 1.0f / (1.0f + __expf(-x)); }

// -------- f32 -> bf16 convert --------
__global__ void cvt_kernel(const float* __restrict__ src, u16* __restrict__ dst, int n) {
  int i = ((int)blockIdx.x * 256 + (int)threadIdx.x) * 4;
  if (i + 4 <= n) {
    const float4 v = *(const float4*)(src + i);
    ushort4 o;
    o.x = f2b(v.x); o.y = f2b(v.y); o.z = f2b(v.z); o.w = f2b(v.w);
    *(ushort4*)(dst + i) = o;
  }
}

// -------- token transpose: xT[t][b] = x[b][t] --------
__global__ void xt_kernel(const int* __restrict__ x, int* __restrict__ xT) {
  const int t = (int)blockIdx.x, b = (int)threadIdx.x;
  xT[t * BATCH + b] = x[b * T_LEN + t];
}

// -------- persistent RNN, decoupled chains (R13 rings/flags) --------
// R18: (1) dependency-free compute phase FIRST (L0: emb-part, L1: hh-part),
// poll hidden behind it; uniform 8-wave K-split, branch-free 4-group reduction.
// (2) ring store coalesced: LDS bounce -> 128 x 16B global_store_dwordx4 sc0 sc1.
__global__ __launch_bounds__(RNN_THREADS, 1) void rnn_persist_kernel(
    const int* __restrict__ xT, const u16* __restrict__ embtab,
    const u16* __restrict__ A0i_r, const u16* __restrict__ A0i_z, const u16* __restrict__ A0i_n,
    const u16* __restrict__ A0h_r, const u16* __restrict__ A0h_z, const u16* __restrict__ A0h_n,
    const u16* __restrict__ A1i_r, const u16* __restrict__ A1i_z, const u16* __restrict__ A1i_n,
    const u16* __restrict__ A1h_r, const u16* __restrict__ A1h_z, const u16* __restrict__ A1h_n,
    const float* __restrict__ bih0, const float* __restrict__ bhh0,
    const float* __restrict__ bih1, const float* __restrict__ bhh1,
    u16* __restrict__ h0r, u16* __restrict__ h1r,
    u16* __restrict__ h1all, unsigned* __restrict__ sync)
{
  __shared__ __align__(16) float lds[16384];
  const int tid = (int)threadIdx.x;
  const int wv = tid >> 6;
  const int lane = tid & 63;
  const int lrow = lane & 15;
  const int lk8 = (lane >> 4) << 3;
  const int wgid = (int)blockIdx.x;
  const int layer = wgid >> 6;
  const int ubase = (wgid & 63) << 4;
  unsigned* p0 = sync;
  unsigned* p1 = sync + 64 * 32;

  // ---- per-gate weight bases: x-part and h-part (R6-safe separate args) ----
  const u16 *Axr, *Axz, *Axn, *Ahr, *Ahz, *Ahn;
  int ldx;
  if (layer == 0) { Axr = A0i_r; Axz = A0i_z; Axn = A0i_n;
                    Ahr = A0h_r; Ahz = A0h_z; Ahn = A0h_n; ldx = EMB_D; }
  else            { Axr = A1i_r; Axz = A1i_z; Axn = A1i_n;
                    Ahr = A1h_r; Ahz = A1h_z; Ahn = A1h_n; ldx = HID; }
  const size_t axrow = (size_t)(ubase + lrow) * ldx;
  const size_t ahrow = (size_t)(ubase + lrow) * HID;
  const int k0e = wv * 64;    // L0 emb K-slice (8 waves x 64 = 512)
  const int k0h = wv * 128;   // h / L1-ih K-slice (8 waves x 128 = 1024)

  // ---- epilogue constants: thread owns unit-pair (u0,u0+1) x batch eb ----
  const float* bi = layer ? bih1 : bih0;
  const float* bh = layer ? bhh1 : bhh0;
  const int u0 = (tid & 7) * 2;
  const int eb = tid >> 3;
  const int eug0 = ubase + u0, eug1 = eug0 + 1;
  const float bR0 = bi[eug0] + bh[eug0];
  const float bZ0 = bi[HID + eug0] + bh[HID + eug0];
  const float bNi0 = bi[2 * HID + eug0];
  const float bNh0 = bh[2 * HID + eug0];
  const float bR1 = bi[eug1] + bh[eug1];
  const float bZ1 = bi[HID + eug1] + bh[HID + eug1];
  const float bNi1 = bi[2 * HID + eug1];
  const float bNh1 = bh[2 * HID + eug1];
  const int l_e = ((u0 >> 2) << 4) | (eb & 15);
  const int r0 = u0 & 3, r1 = r0 + 1;
  const int ebt = eb >> 4;
  const int ix0 = l_e ^ (r0 << 3), ix1 = l_e ^ (r1 << 3);
  float hp0 = 0.f, hp1 = 0.f;

  const int sBeg = (layer == 0) ? 0 : 1;
  const int sEnd = (layer == 0) ? (T_LEN - 1) : T_LEN;

  for (int s = sBeg; s <= sEnd; ++s) {
    const u16* h0prev = h0r + (size_t)((s - 1) & (R0 - 1)) * SLOT;
    const u16* h1prev = h1r + (size_t)((s - 2) & (R1 - 1)) * SLOT;

    f32x4 aR[4], aZ[4], aNi[4], aNh[4];
#pragma unroll
    for (int bt = 0; bt < 4; ++bt) {
      aR[bt] = (f32x4){0.f, 0.f, 0.f, 0.f};
      aZ[bt] = (f32x4){0.f, 0.f, 0.f, 0.f};
      aNi[bt] = (f32x4){0.f, 0.f, 0.f, 0.f};
      aNh[bt] = (f32x4){0.f, 0.f, 0.f, 0.f};
    }

    if (layer == 0) {
      // ---- phase A (dependency-free): emb-part -> r,z,ni ----
      const u16* brow[4];
#pragma unroll
      for (int bt = 0; bt < 4; ++bt) {
        const int tok = xT[s * BATCH + bt * 16 + lrow];
        brow[bt] = embtab + (size_t)tok * EMB_D;
      }
#pragma unroll
      for (int ks = 0; ks < 2; ++ks) {
        const int kk = k0e + ks * 32 + lk8;
        const short8 ar = *(const short8*)(Axr + axrow + kk);
        const short8 az = *(const short8*)(Axz + axrow + kk);
        const short8 an = *(const short8*)(Axn + axrow + kk);
#pragma unroll
        for (int bt = 0; bt < 4; ++bt) {
          const short8 bf = *(const short8*)(brow[bt] + kk);
          aR[bt] = MFMA16(ar, bf, aR[bt]);
          aZ[bt] = MFMA16(az, bf, aZ[bt]);
          aNi[bt] = MFMA16(an, bf, aNi[bt]);
        }
      }
      // ---- poll h0(s-1) (+ ring back-pressure), hidden behind phase A ----
      if (tid < 128) {
        unsigned* f; unsigned tgt;
        if (tid < 64) { f = p0 + (size_t)tid * 32; tgt = (unsigned)s; }
        else { f = p1 + (size_t)(tid - 64) * 32;
               tgt = (s >= 252) ? (unsigned)(s - 250) : 0u; }
        while (__hip_atomic_load(f, __ATOMIC_RELAXED, __HIP_MEMORY_SCOPE_AGENT) < tgt)
          __builtin_amdgcn_s_sleep(1);
      }
      __syncthreads();
      // ---- phase B: h-part -> r,z,nh ----
#pragma unroll
      for (int ks = 0; ks < 4; ++ks) {
        const int kk = k0h + ks * 32 + lk8;
        const short8 ar = *(const short8*)(Ahr + ahrow + kk);
        const short8 az = *(const short8*)(Ahz + ahrow + kk);
        const short8 an = *(const short8*)(Ahn + ahrow + kk);
#pragma unroll
        for (int bt = 0; bt < 4; ++bt) {
          const short8 bf = *(const short8*)(h0prev + (size_t)(bt * 16 + lrow) * HID + kk);
          aR[bt] = MFMA16(ar, bf, aR[bt]);
          aZ[bt] = MFMA16(az, bf, aZ[bt]);
          aNh[bt] = MFMA16(an, bf, aNh[bt]);
        }
      }
    } else {
      // ---- poll h1(s-2) (2-step slack, usually ready) ----
      if (tid >= 64 && tid < 128) {
        unsigned* f = p1 + (size_t)(tid - 64) * 32;
        const unsigned tgt = (unsigned)(s - 1);
        while (__hip_atomic_load(f, __ATOMIC_RELAXED, __HIP_MEMORY_SCOPE_AGENT) < tgt)
          __builtin_amdgcn_s_sleep(1);
      }
      __syncthreads();
      // ---- phase A: hh-part -> r,z,nh ----
#pragma unroll
      for (int ks = 0; ks < 4; ++ks) {
        const int kk = k0h + ks * 32 + lk8;
        const short8 ar = *(const short8*)(Ahr + ahrow + kk);
        const short8 az = *(const short8*)(Ahz + ahrow + kk);
        const short8 an = *(const short8*)(Ahn + ahrow + kk);
#pragma unroll
        for (int bt = 0; bt < 4; ++bt) {
          const short8 bf = *(const short8*)(h1prev + (size_t)(bt * 16 + lrow) * HID + kk);
          aR[bt] = MFMA16(ar, bf, aR[bt]);
          aZ[bt] = MFMA16(az, bf, aZ[bt]);
          aNh[bt] = MFMA16(an, bf, aNh[bt]);
        }
      }
      // ---- poll h0(s-1), hidden behind phase A ----
      if (tid < 64) {
        unsigned* f = p0 + (size_t)tid * 32;
        const unsigned tgt = (unsigned)s;
        while (__hip_atomic_load(f, __ATOMIC_RELAXED, __HIP_MEMORY_SCOPE_AGENT) < tgt)
          __builtin_amdgcn_s_sleep(1);
      }
      __syncthreads();
      // ---- phase B: ih-part -> r,z,ni ----
#pragma unroll
      for (int ks = 0; ks < 4; ++ks) {
        const int kk = k0h + ks * 32 + lk8;
        const short8 ar = *(const short8*)(Axr + axrow + kk);
        const short8 az = *(const short8*)(Axz + axrow + kk);
        const short8 an = *(const short8*)(Axn + axrow + kk);
#pragma unroll
        for (int bt = 0; bt < 4; ++bt) {
          const short8 bf = *(const short8*)(h0prev + (size_t)(bt * 16 + lrow) * HID + kk);
          aR[bt] = MFMA16(ar, bf, aR[bt]);
          aZ[bt] = MFMA16(az, bf, aZ[bt]);
          aNi[bt] = MFMA16(an, bf, aNi[bt]);
        }
      }
    }

    // ---- reduction: branch-free 4 groups x 2 rounds (XOR-swizzled) ----
    if (wv < 4) {
#pragma unroll
      for (int bt = 0; bt < 4; ++bt)
#pragma unroll
        for (int r = 0; r < 4; ++r) {
          const int ix = lane ^ (r << 3);
          lds[(((wv * 4 + 0) * 4 + bt) * 256) + r * 64 + ix] = aR[bt][r];
          lds[(((wv * 4 + 1) * 4 + bt) * 256) + r * 64 + ix] = aZ[bt][r];
          lds[(((wv * 4 + 2) * 4 + bt) * 256) + r * 64 + ix] = aNi[bt][r];
          lds[(((wv * 4 + 3) * 4 + bt) * 256) + r * 64 + ix] = aNh[bt][r];
        }
    }
    __syncthreads();
    if (wv >= 4) {
      const int z = wv - 4;
#pragma unroll
      for (int bt = 0; bt < 4; ++bt)
#pragma unroll
        for (int r = 0; r < 4; ++r) {
          const int ix = lane ^ (r << 3);
          float* q0 = &lds[(((z * 4 + 0) * 4 + bt) * 256) + r * 64 + ix];
          float* q1 = &lds[(((z * 4 + 1) * 4 + bt) * 256) + r * 64 + ix];
          float* q2 = &lds[(((z * 4 + 2) * 4 + bt) * 256) + r * 64 + ix];
          float* q3 = &lds[(((z * 4 + 3) * 4 + bt) * 256) + r * 64 + ix];
          *q0 = *q0 + aR[bt][r];
          *q1 = *q1 + aZ[bt][r];
          *q2 = *q2 + aNi[bt][r];
          *q3 = *q3 + aNh[bt][r];
        }
    }
    __syncthreads();

    // ---- epilogue: gate math (validated decode-0 reads) ----
    unsigned packed;
    {
      float sr0 = 0.f, sz0 = 0.f, sni0 = 0.f, snh0 = 0.f;
      float sr1 = 0.f, sz1 = 0.f, sni1 = 0.f, snh1 = 0.f;
#pragma unroll
      for (int z = 0; z < 4; ++z) {
        sr0  += lds[(((z * 4 + 0) * 4 + ebt) * 256) + r0 * 64 + ix0];
        sz0  += lds[(((z * 4 + 1) * 4 + ebt) * 256) + r0 * 64 + ix0];
        sni0 += lds[(((z * 4 + 2) * 4 + ebt) * 256) + r0 * 64 + ix0];
        snh0 += lds[(((z * 4 + 3) * 4 + ebt) * 256) + r0 * 64 + ix0];
        sr1  += lds[(((z * 4 + 0) * 4 + ebt) * 256) + r1 * 64 + ix1];
        sz1  += lds[(((z * 4 + 1) * 4 + ebt) * 256) + r1 * 64 + ix1];
        sni1 += lds[(((z * 4 + 2) * 4 + ebt) * 256) + r1 * 64 + ix1];
        snh1 += lds[(((z * 4 + 3) * 4 + ebt) * 256) + r1 * 64 + ix1];
      }
      const float rg0 = sigm(sr0 + bR0);
      const float zg0 = sigm(sz0 + bZ0);
      const float ng0 = tanhf(sni0 + bNi0 + rg0 * (snh0 + bNh0));
      const float hn0 = (1.0f - zg0) * ng0 + zg0 * hp0;
      const float rg1 = sigm(sr1 + bR1);
      const float zg1 = sigm(sz1 + bZ1);
      const float ng1 = tanhf(sni1 + bNi1 + rg1 * (snh1 + bNh1));
      const float hn1 = (1.0f - zg1) * ng1 + zg1 * hp1;
      hp0 = hn0; hp1 = hn1;
      packed = (unsigned)f2b(hn0) | ((unsigned)f2b(hn1) << 16);
    }
    // ---- coalesced ring store: LDS bounce -> 128 x 16B sc0sc1 line stores ----
    __syncthreads();                      // all epilogue LDS reads complete
    {
      u16* stag = (u16*)lds;              // 2 KB staging overlay
      *(unsigned*)&stag[eb * 16 + u0] = packed;
    }
    __syncthreads();
    u16* wslot = layer ? (h1r + (size_t)((s - 1) & (R1 - 1)) * SLOT)
                       : (h0r + (size_t)(s & (R0 - 1)) * SLOT);
    if (tid < 128) {
      const int b = tid >> 1, half = tid & 1;
      const int4v d = *(const int4v*)((const char*)lds + b * 32 + half * 16);
      const unsigned long long dst =
          (unsigned long long)(uintptr_t)(wslot + (size_t)b * HID + ubase + half * 8);
      asm volatile("global_store_dwordx4 %0, %1, off sc0 sc1"
                   :: "v"(dst), "v"(d) : "memory");
    }
    __syncthreads();                      // drains the sc stores (vmcnt 0)
    if (tid == 0) {
      unsigned* f = layer ? (p1 + (size_t)(wgid - 64) * 32) : (p0 + (size_t)wgid * 32);
      __hip_atomic_store(f, (unsigned)(s + (layer ? 0 : 1)), __ATOMIC_RELAXED,
                         __HIP_MEMORY_SCOPE_AGENT);
    }
    if (layer)  // streaming store off the critical path
      *(unsigned*)&h1all[((size_t)(s - 1) * BATCH + eb) * HID + eug0] = packed;
  }
}

// -------- epilogue logits (R5-verified MFMA path, decode-0) --------
__global__ __launch_bounds__(256, 2) void logits_kernel(
    const u16* __restrict__ h1all, const u16* __restrict__ Woutb,
    const float* __restrict__ bout, float* __restrict__ out)
{
  __shared__ __align__(16) short lds[16 * 4 * 64 * 8];
  const int tid = (int)threadIdx.x;
  const int wv = tid >> 6, lane = tid & 63;
  const int lrow = lane & 15, lk8 = (lane >> 4) << 3;
  const int row0 = (int)blockIdx.x * 64 + wv * 16;
  f32x4 acc[16];
#pragma unroll
  for (int i = 0; i < 16; ++i) acc[i] = (f32x4){0.f, 0.f, 0.f, 0.f};

  for (int kc = 0; kc < HID; kc += 128) {
    __syncthreads();
#pragma unroll
    for (int j = 0; j < 16; ++j) {
      const int slot = tid + j * 256;
      const int ct = slot >> 8, kt = (slot >> 6) & 3, l = slot & 63;
      *(short8*)&lds[slot * 8] =
          *(const short8*)(Woutb + (size_t)(ct * 16 + (l & 15)) * HID + kc + kt * 32 + ((l >> 4) << 3));
    }
    __syncthreads();
#pragma unroll
    for (int kt = 0; kt < 4; ++kt) {
      const short8 af = *(const short8*)(h1all + (size_t)(row0 + lrow) * HID + kc + kt * 32 + lk8);
#pragma unroll
      for (int ct = 0; ct < 16; ++ct) {
        const short8 bf = *(const short8*)&lds[((ct * 4 + kt) * 64 + lane) * 8];
        acc[ct] = MFMA16(af, bf, acc[ct]);
      }
    }
  }
#pragma unroll
  for (int ct = 0; ct < 16; ++ct) {
    const int v = ct * 16 + lrow;
    const float bo = bout[v];
#pragma unroll
    for (int r = 0; r < 4; ++r) {
      const int row = row0 + (lane >> 4) * 4 + r;  // row = t*64 + b
      const int t = row >> 6, b = row & 63;
      out[((size_t)(b * T_LEN + t)) * VOC + v] = acc[ct][r] + bo;
    }
  }
}

extern "C" void kernel_launch(void* const* d_in, const int* in_sizes, int n_in,
                              void* d_out, int out_size, void* d_ws, size_t ws_size,
                              hipStream_t stream) {
  const int*   x     = (const int*)d_in[0];
  const float* embed = (const float*)d_in[1];
  const float* Wih0  = (const float*)d_in[2];
  const float* Whh0  = (const float*)d_in[3];
  const float* bih0  = (const float*)d_in[4];
  const float* bhh0  = (const float*)d_in[5];
  const float* Wih1  = (const float*)d_in[6];
  const float* Whh1  = (const float*)d_in[7];
  const float* bih1  = (const float*)d_in[8];
  const float* bhh1  = (const float*)d_in[9];
  const float* Wout  = (const float*)d_in[10];
  const float* bout  = (const float*)d_in[11];
  float* out = (float*)d_out;
  char* ws = (char*)d_ws;
  if (ws_size < (size_t)WS_TOTAL) return;

  // zero: h0 ring slot 255 (h0(-1)=0), h1 ring slot 7 (h1(-1)=0), flags
  hipMemsetAsync(ws + OFF_H0R + (size_t)(R0 - 1) * SLOT * 2, 0, SLOT * 2, stream);
  hipMemsetAsync(ws + OFF_H1R + (size_t)(R1 - 1) * SLOT * 2, 0, SLOT * 2, stream);
  hipMemsetAsync(ws + OFF_SYNC, 0, SYNC_BYTES, stream);
  xt_kernel<<<512, 64, 0, stream>>>(x, (int*)(ws + OFF_XT));
  cvt_kernel<<<128, 256, 0, stream>>>(embed, (u16*)(ws + OFF_EMBT), 256 * 512);
  cvt_kernel<<<1536, 256, 0, stream>>>(Wih0, (u16*)(ws + OFF_WIH0), 3072 * 512);
  cvt_kernel<<<3072, 256, 0, stream>>>(Whh0, (u16*)(ws + OFF_WHH0), 3072 * 1024);
  cvt_kernel<<<3072, 256, 0, stream>>>(Wih1, (u16*)(ws + OFF_WIH1), 3072 * 1024);
  cvt_kernel<<<3072, 256, 0, stream>>>(Whh1, (u16*)(ws + OFF_WHH1), 3072 * 1024);
  cvt_kernel<<<256, 256, 0, stream>>>(Wout, (u16*)(ws + OFF_WOUT), 256 * 1024);

  const u16* wih0b = (const u16*)(ws + OFF_WIH0);
  const u16* whh0b = (const u16*)(ws + OFF_WHH0);
  const u16* wih1b = (const u16*)(ws + OFF_WIH1);
  const u16* whh1b = (const u16*)(ws + OFF_WHH1);

  rnn_persist_kernel<<<NWG, RNN_THREADS, 0, stream>>>(
      (const int*)(ws + OFF_XT), (const u16*)(ws + OFF_EMBT),
      wih0b, wih0b + 524288, wih0b + 1048576,
      whh0b, whh0b + 1048576, whh0b + 2097152,
      wih1b, wih1b + 1048576, wih1b + 2097152,
      whh1b, whh1b + 1048576, whh1b + 2097152,
      bih0, bhh0, bih1, bhh1,
      (u16*)(ws + OFF_H0R), (u16*)(ws + OFF_H1R),
      (u16*)(ws + OFF_H1ALL), (unsigned*)(ws + OFF_SYNC));

  logits_kernel<<<512, 256, 0, stream>>>((const u16*)(ws + OFF_H1ALL),
                                         (const u16*)(ws + OFF_WOUT), bout, out);
}